// Round 9
// baseline (243.906 us; speedup 1.0000x reference)
//
#include <hip/hip_runtime.h>
#include <hip/hip_bf16.h>

#define BN    4
#define NN    2048
#define INF   128
#define HH    8
#define HD    16
#define ALPHA 0.2f
#define DECAY 0.1f

// exp2 folding: w2 = log2e * exp(-DECAY*(ct-t)) = exp2(fma(DLOG2E, t, c0)),
// c0 = -DLOG2E*ct + log2(log2e). Then p = exp2(sc * w2).
#define DLOG2E 0.14426950408889634f   // DECAY * log2(e)
#define LLOG2E 0.5287663729448977f    // log2(log2(e))

typedef __attribute__((ext_vector_type(8))) short short8;
typedef __attribute__((ext_vector_type(4))) float float4v;

// ---------------- Kernel 1: fused [max over tm] + [proj h_t/es/ed] ---------
__launch_bounds__(256, 8)
__global__ void k_setup(const float* __restrict__ x,
                        const float* __restrict__ W,
                        const float* __restrict__ a,
                        const float* __restrict__ tm,
                        unsigned* __restrict__ ct,
                        __hip_bfloat16* __restrict__ h_t,
                        float* __restrict__ es, float* __restrict__ ed) {
    if (blockIdx.x < 1024) {
        // ct = max(tm); values >= 0 so u32-compare == f32-compare
        const uint4* p = (const uint4*)tm;
        const int nvec = BN * NN * NN / 4;
        int idx = blockIdx.x * 256 + threadIdx.x;
        const int stride = 1024 * 256;
        unsigned m = 0u;
        for (int i = idx; i < nvec; i += stride) {
            uint4 v = p[i];
            m = max(m, v.x); m = max(m, v.y); m = max(m, v.z); m = max(m, v.w);
        }
        float fm = __uint_as_float(m);
        #pragma unroll
        for (int o = 32; o >= 1; o >>= 1) fm = fmaxf(fm, __shfl_xor(fm, o));
        __shared__ float sm[4];
        if ((threadIdx.x & 63) == 0) sm[threadIdx.x >> 6] = fm;
        __syncthreads();
        if (threadIdx.x == 0) {
            float mm = fmaxf(fmaxf(sm[0], sm[1]), fmaxf(sm[2], sm[3]));
            atomicMax(ct, __float_as_uint(mm));
        }
    } else {
        int bid = blockIdx.x - 1024;          // 0..4095
        int sub = threadIdx.x >> 7;
        int tt  = threadIdx.x & 127;
        int nn  = bid * 2 + sub;              // b*NN+n
        __shared__ float xs[2][INF];
        xs[sub][tt] = x[(size_t)nn * INF + tt];
        __syncthreads();
        int h = tt >> 4, d = tt & 15;
        const float* Wp = W + (h * INF) * HD + d;
        float acc = 0.f;
        #pragma unroll 16
        for (int i = 0; i < INF; i++) acc += xs[sub][i] * Wp[i * HD];
        int b = nn >> 11, n = nn & 2047;
        h_t[((size_t)((b * HH + h) * HD + d)) * NN + n] = __float2bfloat16(acc);
        float s  = acc * a[h * 2 * HD + d];
        float dd = acc * a[h * 2 * HD + HD + d];
        #pragma unroll
        for (int o = 8; o >= 1; o >>= 1) { s += __shfl_xor(s, o); dd += __shfl_xor(dd, o); }
        if (d == 0) {
            es[(b * HH + h) * NN + n] = s;
            ed[(b * HH + h) * NN + n] = dd;
        }
    }
}

// ---------------- Kernel 2: fused scores + softmax + PV (MFMA) -------------
// grid: B * 2(head-group) * 128(i-tile) = 1024 blocks; block: 256 thr =
// 4 waves, wave = one head of the group. 4 blocks/CU resident.
// Rationale (r5-r8 evidence): occupancy 35-72% is perf-neutral; the limiter
// is all-wave barrier drains (syncthreads forces vmcnt(0)). Smaller barrier
// scope (4 waves) + 4 independent block phases per CU reduce the drain
// serialization. Staging tile (head-independent w2) duplicated 2x per
// (b,i-tile) -- negligible. Single-buffer 2-barrier order (r5, fastest).
// Per-round global loads (ed x8, ht x4 dwordx4) hoisted into locals for
// back-to-back issue. Row sums via ones-MFMA; perm-pack round-half-up bf16.
__launch_bounds__(256, 4)
__global__ void k_attn(const int* __restrict__ adj,
                       const float* __restrict__ tm,
                       const __hip_bfloat16* __restrict__ h_t,
                       const float* __restrict__ es, const float* __restrict__ ed,
                       const unsigned* __restrict__ ctp,
                       float* __restrict__ out) {
    int t    = threadIdx.x;
    int wv4  = t >> 6;            // wave 0..3
    int lane = t & 63;
    int q    = lane >> 4;         // quad 0..3
    int im   = lane & 15;         // i within tile / d for B-frag
    int bx   = blockIdx.x;
    int b    = bx >> 9;
    int hg   = (bx >> 8) & 1;     // head group
    int i0   = (bx & 255) >> 1;   // hmm -- see decode below
    // decode: bx = ((b*2 + hg) << 7) | itile
    int itile = bx & 127;
    hg = (bx >> 7) & 1;
    b  = bx >> 8;
    i0 = itile << 4;
    int head = hg * 4 + wv4;
    int i    = i0 + im;
    const int R = 16;             // 16 rounds x 128 j

    __shared__ float tws[16 * 128];   // swizzled single buffer (8 KB)

    float ctv = __uint_as_float(*ctp);
    float c0  = fmaf(-DLOG2E, ctv, LLOG2E);
    float es_i = es[(b * HH + head) * NN + i];

    const float* ed_p = ed + (size_t)(b * HH + head) * NN + q * 8;
    const __hip_bfloat16* ht_p = h_t + ((size_t)((b * HH + head) * HD + im)) * NN + q * 8;

    // staging map: 256 threads x 8 floats = 16 rows x 32 16B-blocks (2/thread)
    int srow  = t >> 4;                      // 0..15
    int sblk0 = (t & 15) << 1;               // logical 16B blocks sblk0, sblk0+1
    int soff0 = srow * 128 + ((sblk0 ^ (srow & 7)) << 2);
    int soff1 = srow * 128 + (((sblk0 + 1) ^ (srow & 7)) << 2);
    const int*   adj_s = adj + ((size_t)(b * NN + i0 + srow)) * NN + (sblk0 << 2);
    const float* tm_s  = tm  + ((size_t)(b * NN + i0 + srow)) * NN + (sblk0 << 2);

    // per-lane swizzled read base
    int rbase = im * 128;
    int rx    = im & 7;

    // all-ones bf16 B fragment for row sums
    union { uint4 u; short8 v; } ones;
    ones.u = make_uint4(0x3F803F80u, 0x3F803F80u, 0x3F803F80u, 0x3F803F80u);

    float4v acc  = {0.f, 0.f, 0.f, 0.f};
    float4v accl = {0.f, 0.f, 0.f, 0.f};

    // prologue: load round-0 staging data
    int4   pa0 = *(const int4*)(adj_s);
    int4   pa1 = *(const int4*)(adj_s + 4);
    float4 pt0 = *(const float4*)(tm_s);
    float4 pt1 = *(const float4*)(tm_s + 4);

    for (int r = 0; r < R; r++) {
        // compute w' for round r (data prefetched in round r-1 / prologue)
        float w00 = (pa0.x != 0) ? exp2f(fmaf(DLOG2E, pt0.x, c0)) : 0.f;
        float w01_ = (pa0.y != 0) ? exp2f(fmaf(DLOG2E, pt0.y, c0)) : 0.f;
        float w02 = (pa0.z != 0) ? exp2f(fmaf(DLOG2E, pt0.z, c0)) : 0.f;
        float w03 = (pa0.w != 0) ? exp2f(fmaf(DLOG2E, pt0.w, c0)) : 0.f;
        float w10 = (pa1.x != 0) ? exp2f(fmaf(DLOG2E, pt1.x, c0)) : 0.f;
        float w11 = (pa1.y != 0) ? exp2f(fmaf(DLOG2E, pt1.y, c0)) : 0.f;
        float w12 = (pa1.z != 0) ? exp2f(fmaf(DLOG2E, pt1.z, c0)) : 0.f;
        float w13 = (pa1.w != 0) ? exp2f(fmaf(DLOG2E, pt1.w, c0)) : 0.f;

        __syncthreads();   // all waves done consuming round r-1 tile
        *(float4*)&tws[soff0] = make_float4(w00, w01_, w02, w03);
        *(float4*)&tws[soff1] = make_float4(w10, w11, w12, w13);
        if (r + 1 < R) {   // prefetch round r+1 staging data
            pa0 = *(const int4*)(adj_s + (r + 1) * 128);
            pa1 = *(const int4*)(adj_s + (r + 1) * 128 + 4);
            pt0 = *(const float4*)(tm_s + (r + 1) * 128);
            pt1 = *(const float4*)(tm_s + (r + 1) * 128 + 4);
        }
        __syncthreads();   // tile r visible

        // hoist all of round r's global loads (12 dwordx4) for ILP
        float4 E0[4], E1[4];
        uint4  HV[4];
        #pragma unroll
        for (int c4 = 0; c4 < 4; c4++) {
            int jg = r * 128 + c4 * 32;
            E0[c4] = *(const float4*)(ed_p + jg);
            E1[c4] = *(const float4*)(ed_p + jg + 4);
            HV[c4] = *(const uint4*)(ht_p + jg);
        }

        #pragma unroll
        for (int c4 = 0; c4 < 4; c4++) {
            int blk0 = c4 * 8 + 2 * q;
            float4 wA = *(const float4*)&tws[rbase + ((blk0 ^ rx) << 2)];
            float4 wB = *(const float4*)&tws[rbase + (((blk0 + 1) ^ rx) << 2)];

            float wvv[8] = {wA.x, wA.y, wA.z, wA.w, wB.x, wB.y, wB.z, wB.w};
            float evv[8] = {E0[c4].x, E0[c4].y, E0[c4].z, E0[c4].w,
                            E1[c4].x, E1[c4].y, E1[c4].z, E1[c4].w};

            unsigned u[8];
            #pragma unroll
            for (int k = 0; k < 8; k++) {
                float s0 = es_i + evv[k];
                float sc = fmaxf(s0, ALPHA * s0);      // leaky_relu
                float pv = exp2f(sc * wvv[k]);         // w pre-scaled by log2e
                unsigned b16 = __float_as_uint(pv) + 0x8000u;  // round-half-up
                u[k] = (wvv[k] > 0.f) ? b16 : 0u;      // masked -> 0
            }
            union { uint4 w; short8 v; } af;
            af.w.x = __builtin_amdgcn_perm(u[1], u[0], 0x07060302u);
            af.w.y = __builtin_amdgcn_perm(u[3], u[2], 0x07060302u);
            af.w.z = __builtin_amdgcn_perm(u[5], u[4], 0x07060302u);
            af.w.w = __builtin_amdgcn_perm(u[7], u[6], 0x07060302u);

            union { uint4 u; short8 v; } bf;
            bf.u = HV[c4];
            acc  = __builtin_amdgcn_mfma_f32_16x16x32_bf16(af.v, bf.v, acc, 0, 0, 0);
            accl = __builtin_amdgcn_mfma_f32_16x16x32_bf16(af.v, ones.v, accl, 0, 0, 0);
        }
    }

    // D layout: col = lane&15, row = q*4 + reg. accl cols all equal l(row):
    // normalize + ELU + store directly, no cross-lane traffic.
    #pragma unroll
    for (int r = 0; r < 4; r++) {
        int row = q * 4 + r;
        float v = acc[r] / accl[r];
        v = (v > 0.f) ? v : expm1f(v);   // ELU (alpha=1)
        out[((size_t)(b * NN + i0 + row)) * (HH * HD) + head * HD + im] = v;
    }
}

extern "C" void kernel_launch(void* const* d_in, const int* in_sizes, int n_in,
                              void* d_out, int out_size, void* d_ws, size_t ws_size,
                              hipStream_t stream) {
    const float* x   = (const float*)d_in[0];
    const int*   adj = (const int*)d_in[1];
    const float* tm  = (const float*)d_in[2];
    const float* W   = (const float*)d_in[3];
    const float* a   = (const float*)d_in[4];
    float* out = (float*)d_out;

    float* wsf = (float*)d_ws;
    unsigned* ct = (unsigned*)wsf;
    float* es = wsf + 64;                                    // 65,536
    float* ed = es + BN * HH * NN;                           // 65,536
    __hip_bfloat16* h_t = (__hip_bfloat16*)(ed + BN * HH * NN);  // 1,048,576 bf16

    hipMemsetAsync(d_ws, 0, 4, stream);                      // ct = 0.0f
    k_setup<<<1024 + 4096, 256, 0, stream>>>(x, W, a, tm, ct, h_t, es, ed);
    k_attn <<<BN * 2 * (NN / 16), 256, 0, stream>>>(adj, tm, h_t, es, ed, ct, out);
}